// Round 1
// baseline (163.824 us; speedup 1.0000x reference)
//
#include <hip/hip_runtime.h>

#define BB   256
#define NIMG 49
#define NGPS 32
#define DIM  256
#define MPAD 64

typedef __attribute__((ext_vector_type(8))) __bf16 bf16x8;
typedef __attribute__((ext_vector_type(4))) float  f32x4;
typedef __attribute__((ext_vector_type(4))) unsigned short u16x4;

__device__ inline unsigned short f2bf(float f) {
  unsigned int u = __float_as_uint(f);
  u += 0x7fff + ((u >> 16) & 1);   // round-to-nearest-even
  return (unsigned short)(u >> 16);
}

// ---------------- kernel 1: L2-normalize + cast to bf16 (img padded to 64 rows/b) ----
__global__ __launch_bounds__(256) void norm_kernel(
    const float* __restrict__ img, const float* __restrict__ gps,
    unsigned short* __restrict__ imgN, unsigned short* __restrict__ gpsN)
{
  int w    = (blockIdx.x * 256 + threadIdx.x) >> 6;  // one wave per row
  int lane = threadIdx.x & 63;
  const float* src;
  unsigned short* dst;
  if (w < BB * MPAD) {
    int b = w >> 6, n = w & 63;
    dst = imgN + (size_t)w * DIM;
    if (n >= NIMG) {                                  // zero padding rows
      u16x4 z = {0, 0, 0, 0};
      *reinterpret_cast<u16x4*>(dst + lane * 4) = z;
      return;
    }
    src = img + ((size_t)b * NIMG + n) * DIM;
  } else {
    int t = w - BB * MPAD;
    dst = gpsN + (size_t)t * DIM;
    src = gps + (size_t)t * DIM;
  }
  f32x4 x = *reinterpret_cast<const f32x4*>(src + lane * 4);
  float ss = x[0]*x[0] + x[1]*x[1] + x[2]*x[2] + x[3]*x[3];
  #pragma unroll
  for (int d = 1; d < 64; d <<= 1) ss += __shfl_xor(ss, d);
  float inv = 1.0f / fmaxf(sqrtf(ss), 1e-12f);
  u16x4 o;
  o[0] = f2bf(x[0]*inv); o[1] = f2bf(x[1]*inv);
  o[2] = f2bf(x[2]*inv); o[3] = f2bf(x[3]*inv);
  *reinterpret_cast<u16x4*>(dst + lane * 4) = o;
}

// ---------------- kernel 2: all-pairs 64x32 MFMA GEMM + fused max/mean reductions ----
// grid: 2048 blocks = 256 b * 8 g-chunks; 4 waves/block, each wave owns whole pairs.
__global__ __launch_bounds__(256, 2) void pair_kernel(
    const unsigned short* __restrict__ imgN, const unsigned short* __restrict__ gpsN,
    float* __restrict__ i2g, float* __restrict__ g2i)
{
  int tid  = threadIdx.x;
  int wv   = tid >> 6;
  int lane = tid & 63;
  int col  = lane & 15, grp = lane >> 4;
  int bid  = blockIdx.x;
  int b = bid >> 3, gc = bid & 7;

  // A fragments: img[b] 64x256 in registers (lane: row=col(lane&15), k=grp*8+j)
  bf16x8 af[4][8];
  {
    const unsigned short* abase = imgN + ((size_t)b * MPAD + col) * DIM + grp * 8;
    #pragma unroll
    for (int mt = 0; mt < 4; ++mt)
      #pragma unroll
      for (int kc = 0; kc < 8; ++kc)
        af[mt][kc] = *reinterpret_cast<const bf16x8*>(abase + mt * 16 * DIM + kc * 32);
  }

  for (int gi = 0; gi < 8; ++gi) {
    int g = gc * 32 + wv + gi * 4;
    const unsigned short* gbase = gpsN + ((size_t)g * NGPS + col) * DIM + grp * 8;

    f32x4 acc[4][2];
    #pragma unroll
    for (int mt = 0; mt < 4; ++mt) {
      acc[mt][0] = (f32x4){0.f, 0.f, 0.f, 0.f};
      acc[mt][1] = (f32x4){0.f, 0.f, 0.f, 0.f};
    }
    #pragma unroll
    for (int kc = 0; kc < 8; ++kc) {
      bf16x8 b0 = *reinterpret_cast<const bf16x8*>(gbase + kc * 32);            // cols 0..15
      bf16x8 b1 = *reinterpret_cast<const bf16x8*>(gbase + 16 * DIM + kc * 32); // cols 16..31
      #pragma unroll
      for (int mt = 0; mt < 4; ++mt) {
        acc[mt][0] = __builtin_amdgcn_mfma_f32_16x16x32_bf16(af[mt][kc], b0, acc[mt][0], 0, 0, 0);
        acc[mt][1] = __builtin_amdgcn_mfma_f32_16x16x32_bf16(af[mt][kc], b1, acc[mt][1], 0, 0, 0);
      }
    }

    // ---- epilogue: D layout col=lane&15, row=mt*16 + grp*4 + reg ----
    // row-max over 32 cols (valid rows: all of mt 0..2; mt3 only row 48 = grp0,reg0)
    float rm[3][4];
    #pragma unroll
    for (int mt = 0; mt < 3; ++mt)
      #pragma unroll
      for (int r = 0; r < 4; ++r)
        rm[mt][r] = fmaxf(acc[mt][0][r], acc[mt][1][r]);
    float rm3 = fmaxf(acc[3][0][0], acc[3][1][0]);
    #pragma unroll
    for (int d = 1; d < 16; d <<= 1) {
      #pragma unroll
      for (int mt = 0; mt < 3; ++mt)
        #pragma unroll
        for (int r = 0; r < 4; ++r)
          rm[mt][r] = fmaxf(rm[mt][r], __shfl_xor(rm[mt][r], d));
      rm3 = fmaxf(rm3, __shfl_xor(rm3, d));
    }
    float rsum = 0.f;
    #pragma unroll
    for (int mt = 0; mt < 3; ++mt)
      #pragma unroll
      for (int r = 0; r < 4; ++r)
        rsum += rm[mt][r];
    if (grp == 0) rsum += rm3;          // row 48
    rsum += __shfl_xor(rsum, 16);
    rsum += __shfl_xor(rsum, 32);

    // col-max over valid rows, then mean over 32 cols
    float cm0 = acc[0][0][0], cm1 = acc[0][1][0];
    #pragma unroll
    for (int mt = 0; mt < 3; ++mt)
      #pragma unroll
      for (int r = 0; r < 4; ++r) {
        if (mt == 0 && r == 0) continue;
        cm0 = fmaxf(cm0, acc[mt][0][r]);
        cm1 = fmaxf(cm1, acc[mt][1][r]);
      }
    if (grp == 0) { cm0 = fmaxf(cm0, acc[3][0][0]); cm1 = fmaxf(cm1, acc[3][1][0]); }
    cm0 = fmaxf(cm0, __shfl_xor(cm0, 16));
    cm0 = fmaxf(cm0, __shfl_xor(cm0, 32));
    cm1 = fmaxf(cm1, __shfl_xor(cm1, 16));
    cm1 = fmaxf(cm1, __shfl_xor(cm1, 32));
    float csum = cm0 + cm1;
    #pragma unroll
    for (int d = 1; d < 16; d <<= 1) csum += __shfl_xor(csum, d);

    if (lane == 0) {
      i2g[b * 256 + g] = rsum * (1.0f / NIMG);
      g2i[g * 256 + b] = csum * (1.0f / NGPS);
    }
  }
}

// ---------------- kernel 3: per-row CE partials -------------------------------------
__global__ __launch_bounds__(256) void ce_kernel(
    const float* __restrict__ i2g, const float* __restrict__ g2i,
    const float* __restrict__ lsp, float* __restrict__ partial)
{
  int b = blockIdx.x, t = threadIdx.x, lane = t & 63, wv = t >> 6;
  float s = fminf(expf(lsp[0]), 100.0f);
  float v1 = s * i2g[b * 256 + t];
  float v2 = s * g2i[b * 256 + t];

  float m1 = v1, m2 = v2;
  #pragma unroll
  for (int d = 1; d < 64; d <<= 1) {
    m1 = fmaxf(m1, __shfl_xor(m1, d));
    m2 = fmaxf(m2, __shfl_xor(m2, d));
  }
  __shared__ float sm[2][4];
  if (lane == 0) { sm[0][wv] = m1; sm[1][wv] = m2; }
  __syncthreads();
  m1 = fmaxf(fmaxf(sm[0][0], sm[0][1]), fmaxf(sm[0][2], sm[0][3]));
  m2 = fmaxf(fmaxf(sm[1][0], sm[1][1]), fmaxf(sm[1][2], sm[1][3]));

  float e1 = expf(v1 - m1), e2 = expf(v2 - m2);
  #pragma unroll
  for (int d = 1; d < 64; d <<= 1) {
    e1 += __shfl_xor(e1, d);
    e2 += __shfl_xor(e2, d);
  }
  __shared__ float se[2][4];
  if (lane == 0) { se[0][wv] = e1; se[1][wv] = e2; }
  __syncthreads();
  if (t == 0) {
    float S1 = se[0][0] + se[0][1] + se[0][2] + se[0][3];
    float S2 = se[1][0] + se[1][1] + se[1][2] + se[1][3];
    float lse1 = m1 + logf(S1);
    float lse2 = m2 + logf(S2);
    partial[b] = (lse1 - s * i2g[b * 257]) + (lse2 - s * g2i[b * 257]);
  }
}

// ---------------- kernel 4: final scalar --------------------------------------------
__global__ __launch_bounds__(256) void finish_kernel(
    const float* __restrict__ partial, float* __restrict__ out)
{
  int t = threadIdx.x, lane = t & 63, wv = t >> 6;
  float v = partial[t];
  #pragma unroll
  for (int d = 1; d < 64; d <<= 1) v += __shfl_xor(v, d);
  __shared__ float sp[4];
  if (lane == 0) sp[wv] = v;
  __syncthreads();
  if (t == 0) out[0] = (sp[0] + sp[1] + sp[2] + sp[3]) * (1.0f / 512.0f);
}

extern "C" void kernel_launch(void* const* d_in, const int* in_sizes, int n_in,
                              void* d_out, int out_size, void* d_ws, size_t ws_size,
                              hipStream_t stream)
{
  const float* img = (const float*)d_in[0];
  const float* gps = (const float*)d_in[1];
  const float* lsp = (const float*)d_in[2];
  float* out = (float*)d_out;
  char* ws = (char*)d_ws;

  unsigned short* imgN = (unsigned short*)(ws);              //  8,388,608 B
  unsigned short* gpsN = (unsigned short*)(ws + 8388608);    //  4,194,304 B
  float* i2g     = (float*)(ws + 12582912);                  //    262,144 B
  float* g2i     = (float*)(ws + 12845056);                  //    262,144 B
  float* partial = (float*)(ws + 13107200);                  //      1,024 B

  norm_kernel<<<6144, 256, 0, stream>>>(img, gps, imgN, gpsN);
  pair_kernel<<<2048, 256, 0, stream>>>(imgN, gpsN, i2g, g2i);
  ce_kernel<<<256, 256, 0, stream>>>(i2g, g2i, lsp, partial);
  finish_kernel<<<1, 256, 0, stream>>>(partial, out);
}